// Round 1
// baseline (1517.037 us; speedup 1.0000x reference)
//
#include <hip/hip_runtime.h>

typedef unsigned short u16;
typedef __bf16 bf16x8 __attribute__((ext_vector_type(8)));
typedef float f32x16 __attribute__((ext_vector_type(16)));
typedef u16 u16x8 __attribute__((ext_vector_type(8)));

constexpr int NE  = 8;
constexpr int KD  = 2048;   // input size (K)
constexpr int ND  = 8192;   // output size (N)
constexpr int TOK = 16384;
constexpr int TPE = TOK / NE;            // 2048 tokens per expert (static balanced routing)
constexpr int BM = 128, BN = 128, BK = 64;
constexpr int LDSS = BK + 8;             // 72: +8 bf16 pad -> only 2-way bank aliasing (free)
constexpr int MT = TPE / BM;             // 16 m-tiles per expert
constexpr int NT = ND / BN;              // 64 n-tiles
constexpr int TILES_PER_E = MT * NT;     // 1024

__device__ __forceinline__ u16 bf16_rne(float f) {
    unsigned u = __float_as_uint(f);
    u += 0x7fffu + ((u >> 16) & 1u);     // round-to-nearest-even
    return (u16)(u >> 16);
}

// fp32 -> bf16 (RNE), 8 elements / thread-iter, pure memory-bound pass
__global__ void cvt_f32_bf16(const float* __restrict__ src, u16* __restrict__ dst, int n8) {
    int stride = gridDim.x * blockDim.x;
    for (int i = blockIdx.x * blockDim.x + threadIdx.x; i < n8; i += stride) {
        float4 v0 = reinterpret_cast<const float4*>(src)[2 * i];
        float4 v1 = reinterpret_cast<const float4*>(src)[2 * i + 1];
        u16x8 o;
        o[0] = bf16_rne(v0.x); o[1] = bf16_rne(v0.y);
        o[2] = bf16_rne(v0.z); o[3] = bf16_rne(v0.w);
        o[4] = bf16_rne(v1.x); o[5] = bf16_rne(v1.y);
        o[6] = bf16_rne(v1.z); o[7] = bf16_rne(v1.w);
        reinterpret_cast<u16x8*>(dst)[i] = o;
    }
}

// Grouped GEMM: C[t, n] = sum_k A[t, k] * W[e(t), n, k]
// 128x128 tile / block, 4 waves in 2x2, each wave 64x64 via 2x2 mfma_32x32x16_bf16 frags.
template <bool FROM_BF16>
__global__ __launch_bounds__(256, 4) void moe_gemm(
    const float* __restrict__ Af, const float* __restrict__ Bf,
    const u16* __restrict__ Ab, const u16* __restrict__ Bb,
    float* __restrict__ C)
{
    __shared__ __align__(16) u16 As[BM * LDSS];
    __shared__ __align__(16) u16 Bs[BN * LDSS];

    const int bx = blockIdx.x;
    const int e  = bx / TILES_PER_E;
    const int rr = bx % TILES_PER_E;
    const int tm = rr % MT;              // vary m fastest: 16 consecutive blocks share B-tile
    const int tn = rr / MT;

    const long arow0 = (long)e * TPE + (long)tm * BM;   // token-row base
    const long brow0 = (long)e * ND  + (long)tn * BN;   // weight-row base (out-dim major)

    const int t    = threadIdx.x;
    const int lane = t & 63;
    const int w    = t >> 6;
    const int wm   = (w >> 1) * 64;
    const int wn   = (w & 1) * 64;
    const int srow = t >> 3;             // staging: 32 rows / pass
    const int scol = (t & 7) * 8;        // staging: 8 contiguous elems / thread
    const int lm   = lane & 31;          // mfma row/col within 32
    const int lk8  = (lane >> 5) * 8;    // mfma k-offset: halves of wave hold k 0-7 / 8-15

    f32x16 acc[2][2] = {};

    for (int kb = 0; kb < KD; kb += BK) {
        __syncthreads();
        #pragma unroll
        for (int p = 0; p < 4; ++p) {
            const int row = srow + p * 32;
            u16x8 av, bv;
            if (FROM_BF16) {
                av = *reinterpret_cast<const u16x8*>(Ab + (arow0 + row) * KD + kb + scol);
                bv = *reinterpret_cast<const u16x8*>(Bb + (brow0 + row) * KD + kb + scol);
            } else {
                const float* ap = Af + (arow0 + row) * KD + kb + scol;
                const float* bp = Bf + (brow0 + row) * KD + kb + scol;
                float4 a0 = reinterpret_cast<const float4*>(ap)[0];
                float4 a1 = reinterpret_cast<const float4*>(ap)[1];
                float4 b0 = reinterpret_cast<const float4*>(bp)[0];
                float4 b1 = reinterpret_cast<const float4*>(bp)[1];
                av[0]=bf16_rne(a0.x); av[1]=bf16_rne(a0.y); av[2]=bf16_rne(a0.z); av[3]=bf16_rne(a0.w);
                av[4]=bf16_rne(a1.x); av[5]=bf16_rne(a1.y); av[6]=bf16_rne(a1.z); av[7]=bf16_rne(a1.w);
                bv[0]=bf16_rne(b0.x); bv[1]=bf16_rne(b0.y); bv[2]=bf16_rne(b0.z); bv[3]=bf16_rne(b0.w);
                bv[4]=bf16_rne(b1.x); bv[5]=bf16_rne(b1.y); bv[6]=bf16_rne(b1.z); bv[7]=bf16_rne(b1.w);
            }
            *reinterpret_cast<u16x8*>(&As[row * LDSS + scol]) = av;
            *reinterpret_cast<u16x8*>(&Bs[row * LDSS + scol]) = bv;
        }
        __syncthreads();
        #pragma unroll
        for (int kk = 0; kk < BK; kk += 16) {
            bf16x8 a0 = *reinterpret_cast<const bf16x8*>(&As[(wm      + lm) * LDSS + kk + lk8]);
            bf16x8 a1 = *reinterpret_cast<const bf16x8*>(&As[(wm + 32 + lm) * LDSS + kk + lk8]);
            bf16x8 b0 = *reinterpret_cast<const bf16x8*>(&Bs[(wn      + lm) * LDSS + kk + lk8]);
            bf16x8 b1 = *reinterpret_cast<const bf16x8*>(&Bs[(wn + 32 + lm) * LDSS + kk + lk8]);
            acc[0][0] = __builtin_amdgcn_mfma_f32_32x32x16_bf16(a0, b0, acc[0][0], 0, 0, 0);
            acc[0][1] = __builtin_amdgcn_mfma_f32_32x32x16_bf16(a0, b1, acc[0][1], 0, 0, 0);
            acc[1][0] = __builtin_amdgcn_mfma_f32_32x32x16_bf16(a1, b0, acc[1][0], 0, 0, 0);
            acc[1][1] = __builtin_amdgcn_mfma_f32_32x32x16_bf16(a1, b1, acc[1][1], 0, 0, 0);
        }
    }

    // C/D layout (m74/m101 verified): col = lane&31, row = (reg&3) + 8*(reg>>2) + 4*(lane>>5)
    const long col0  = (long)tn * BN + wn + lm;
    const int  half4 = (lane >> 5) * 4;
    #pragma unroll
    for (int i = 0; i < 2; ++i) {
        #pragma unroll
        for (int r = 0; r < 16; ++r) {
            const long row = arow0 + wm + i * 32 + (r & 3) + 8 * (r >> 2) + half4;
            #pragma unroll
            for (int j = 0; j < 2; ++j) {
                C[row * ND + col0 + j * 32] = acc[i][j][r];
            }
        }
    }
}

extern "C" void kernel_launch(void* const* d_in, const int* in_sizes, int n_in,
                              void* d_out, int out_size, void* d_ws, size_t ws_size,
                              hipStream_t stream) {
    const float* inputs = (const float*)d_in[0];
    const float* weight = (const float*)d_in[1];
    // d_in[2] = expert_size (int64): static balanced routing (2048/expert) per setup — not read.
    float* out = (float*)d_out;

    const size_t a_elems = (size_t)TOK * KD;          //  33.5M
    const size_t b_elems = (size_t)NE * ND * KD;      // 134.2M
    const size_t need = (a_elems + b_elems) * sizeof(u16);   // 320 MiB
    const int grid = NE * TILES_PER_E;                // 8192 blocks

    if (ws_size >= need) {
        u16* ab = (u16*)d_ws;
        u16* bb = ab + a_elems;
        hipLaunchKernelGGL(cvt_f32_bf16, dim3(2048), dim3(256), 0, stream,
                           inputs, ab, (int)(a_elems / 8));
        hipLaunchKernelGGL(cvt_f32_bf16, dim3(8192), dim3(256), 0, stream,
                           weight, bb, (int)(b_elems / 8));
        hipLaunchKernelGGL((moe_gemm<true>), dim3(grid), dim3(256), 0, stream,
                           nullptr, nullptr, ab, bb, out);
    } else {
        hipLaunchKernelGGL((moe_gemm<false>), dim3(grid), dim3(256), 0, stream,
                           inputs, weight, nullptr, nullptr, out);
    }
}